// Round 4
// baseline (352.763 us; speedup 1.0000x reference)
//
#include <hip/hip_runtime.h>
#include <hip/hip_bf16.h>
#include <math.h>

#define VOCAB 6913
#define NROWS 2048   // B*S = 2*1024

struct Heads { const float* p[7]; };

// One block per (head, row). Two-pass softmax-LSE entirely in registers:
// load row slice into 7 float4 regs, block-max, then sum expf, then NLL.
__global__ __launch_bounds__(256) void row_nll_kernel(Heads h,
                                                      const int* __restrict__ x,
                                                      float* __restrict__ nll) {
  const int bx  = blockIdx.x;
  const int c   = bx >> 11;          // head 0..6
  const int r   = bx & 2047;         // row 0..2047
  const int tid = threadIdx.x;

  const float* rowp = h.p[c] + (size_t)r * VOCAB;

  // Row base misalignment: r*6913 % 4 == r % 4 floats. Peel to 16B alignment.
  const int off  = (4 - (r & 3)) & 3;
  const int n4   = (VOCAB - off) >> 2;           // 1727 or 1728
  const int tail = VOCAB - off - (n4 << 2);      // 0..3
  const float4* row4 = reinterpret_cast<const float4*>(rowp + off);

  float head_v = (tid < off)  ? rowp[tid] : -INFINITY;
  float tail_v = (tid < tail) ? rowp[off + (n4 << 2) + tid] : -INFINITY;

  float4 v[7];
#pragma unroll
  for (int k = 0; k < 7; k++) {
    int j = tid + (k << 8);
    if (j < n4) v[k] = row4[j];
    else        v[k] = make_float4(-INFINITY, -INFINITY, -INFINITY, -INFINITY);
  }

  // ---- pass 1: max ----
  float m = fmaxf(head_v, tail_v);
#pragma unroll
  for (int k = 0; k < 7; k++)
    m = fmaxf(m, fmaxf(fmaxf(v[k].x, v[k].y), fmaxf(v[k].z, v[k].w)));

  __shared__ float redm[4], reds[4];
#pragma unroll
  for (int o = 32; o; o >>= 1) m = fmaxf(m, __shfl_xor(m, o));
  if ((tid & 63) == 0) redm[tid >> 6] = m;
  __syncthreads();
  m = fmaxf(fmaxf(redm[0], redm[1]), fmaxf(redm[2], redm[3]));

  // ---- pass 2: sum exp (registers, no re-read) ----
  float s = expf(head_v - m) + expf(tail_v - m);   // exp(-inf)=0 for inactive lanes
#pragma unroll
  for (int k = 0; k < 7; k++)
    s += expf(v[k].x - m) + expf(v[k].y - m) + expf(v[k].z - m) + expf(v[k].w - m);

#pragma unroll
  for (int o = 32; o; o >>= 1) s += __shfl_xor(s, o);
  if ((tid & 63) == 0) reds[tid >> 6] = s;
  __syncthreads();

  if (tid == 0) {
    s = reds[0] + reds[1] + reds[2] + reds[3];
    const int b = r >> 10, si = r & 1023;
    const int t = x[(b * 1025 + si + 1) * 12 + c];   // target[..., c], in [0,VOCAB)
    const float vt = rowp[t];
    nll[c * NROWS + r] = -(vt - m - logf(s));
  }
}

// Single block: masked sums of the 7 NLL vectors + constant-f0 MSE + outputs.
__global__ __launch_bounds__(256) void finalize_kernel(const int* __restrict__ x,
                                                       const float* __restrict__ nll,
                                                       float* __restrict__ out) {
  const int tid = threadIdx.x;

  // f[...,0] is constant: softmax over size-1 axis == 1, so s == 6.0 and
  // f0 = sum_k d[k,0] = 576 * sum_i sin(-i*pi/6)  (tiny fp32 residue).
  float sum_sin = 0.f;
#pragma unroll
  for (int i = 0; i < 12; i++)
    sum_sin += sinf((float)i * -0.52359877559829887f);
  const float cf = sum_sin * 576.0f;

  float acc[9];  // 0: tv, 1..7: losses, 8: mse
#pragma unroll
  for (int q = 0; q < 9; q++) acc[q] = 0.f;

  for (int r = tid; r < NROWS; r += 256) {
    const int b = r >> 10, si = r & 1023;
    const int* tr = x + (b * 1025 + si + 1) * 12;
    const float mask = (tr[0] != 0) ? 1.f : 0.f;
    acc[0] += mask;
#pragma unroll
    for (int hh = 0; hh < 7; hh++)
      acc[1 + hh] += nll[hh * NROWS + r] * mask;
    const float d = cf - (float)tr[11];
    acc[8] += d * d * mask;
  }

  __shared__ float red[9][4];
#pragma unroll
  for (int q = 0; q < 9; q++) {
    float v = acc[q];
#pragma unroll
    for (int o = 32; o; o >>= 1) v += __shfl_xor(v, o);
    if ((tid & 63) == 0) red[q][tid >> 6] = v;
  }
  __syncthreads();

  if (tid == 0) {
    float tot[9];
#pragma unroll
    for (int q = 0; q < 9; q++)
      tot[q] = red[q][0] + red[q][1] + red[q][2] + red[q][3];
    const float tv  = tot[0];
    const float inv = (tv == 0.f) ? 0.f : 1.f / tv;   // where(tv==0, 0, ·/tv)
#pragma unroll
    for (int hh = 0; hh < 7; hh++) out[hh] = tot[1 + hh] * inv;
    out[7] = tot[8] * inv;
  }
}

extern "C" void kernel_launch(void* const* d_in, const int* in_sizes, int n_in,
                              void* d_out, int out_size, void* d_ws, size_t ws_size,
                              hipStream_t stream) {
  const int* x = (const int*)d_in[0];
  Heads h;
  for (int i = 0; i < 7; i++) h.p[i] = (const float*)d_in[1 + i];

  float* nll = (float*)d_ws;          // 7*2048 floats = 56 KB
  float* out = (float*)d_out;         // 8 floats

  row_nll_kernel<<<7 * NROWS, 256, 0, stream>>>(h, x, nll);
  finalize_kernel<<<1, 256, 0, stream>>>(x, nll, out);
}

// Round 5
// 347.649 us; speedup vs baseline: 1.0147x; 1.0147x over previous
//
#include <hip/hip_runtime.h>
#include <hip/hip_bf16.h>
#include <math.h>

#define VOCAB 6913
#define NROWS 2048   // B*S = 2*1024

struct Heads { const float* p[7]; };

// One block per (head, row). Two-pass softmax-LSE over registers.
// Key changes vs prev round (which ran 130us, VALUBusy 43%, VGPR=24):
//  - __expf/__logf (native v_exp_f32) instead of libm expf/logf
//  - asm keep-alive pins the 28 row values in VGPRs across the barrier
//    (VGPR=24 proved the compiler was re-loading them in pass 2)
//  - k=0..5 slices are provably in-range (tid+1280 <= 1535 < n4 >= 1727):
//    unconditional loads, no -INF cndmask fill; only k=6 is predicated
__global__ __launch_bounds__(256) void row_nll_kernel(Heads h,
                                                      const int* __restrict__ x,
                                                      float* __restrict__ nll) {
  const int bx  = blockIdx.x;
  const int c   = bx >> 11;          // head 0..6
  const int r   = bx & 2047;         // row 0..2047
  const int tid = threadIdx.x;

  const float* rowp = h.p[c] + (size_t)r * VOCAB;

  // Row base misalignment: (r*6913) % 4 == r % 4 floats. Peel to 16B alignment.
  const int off  = (4 - (r & 3)) & 3;
  const int n4   = (VOCAB - off) >> 2;           // 1727 or 1728
  const int tail = VOCAB - off - (n4 << 2);      // 0..3
  const float4* row4 = reinterpret_cast<const float4*>(rowp + off);

  float4 v[7];
#pragma unroll
  for (int k = 0; k < 6; k++) v[k] = row4[tid + (k << 8)];   // always in range
  const bool has6 = (tid + 1536) < n4;                       // 191 or 192 threads
  if (has6) v[6] = row4[tid + 1536];
  else      v[6] = make_float4(0.f, 0.f, 0.f, 0.f);          // defined, never used

  const bool hashead = tid < off;
  const bool hastail = tid < tail;
  float head_v = hashead ? rowp[tid] : 0.f;
  float tail_v = hastail ? rowp[off + (n4 << 2) + tid] : 0.f;

  // ---- pass 1: max (predicated, no -INF fills) ----
  float m = fmaxf(fmaxf(v[0].x, v[0].y), fmaxf(v[0].z, v[0].w));
#pragma unroll
  for (int k = 1; k < 6; k++)
    m = fmaxf(m, fmaxf(fmaxf(v[k].x, v[k].y), fmaxf(v[k].z, v[k].w)));
  if (has6)    m = fmaxf(m, fmaxf(fmaxf(v[6].x, v[6].y), fmaxf(v[6].z, v[6].w)));
  if (hashead) m = fmaxf(m, head_v);
  if (hastail) m = fmaxf(m, tail_v);

  // Pin row values in registers across the barrier (block load rematerialization).
#pragma unroll
  for (int k = 0; k < 7; k++)
    asm volatile("" : "+v"(v[k].x), "+v"(v[k].y), "+v"(v[k].z), "+v"(v[k].w));
  asm volatile("" : "+v"(head_v), "+v"(tail_v));

  __shared__ float redm[4], reds[4];
#pragma unroll
  for (int o = 32; o; o >>= 1) m = fmaxf(m, __shfl_xor(m, o));
  if ((tid & 63) == 0) redm[tid >> 6] = m;
  __syncthreads();
  m = fmaxf(fmaxf(redm[0], redm[1]), fmaxf(redm[2], redm[3]));

  // ---- pass 2: sum exp from registers (native exp) ----
  float s = 0.f;
#pragma unroll
  for (int k = 0; k < 6; k++)
    s += __expf(v[k].x - m) + __expf(v[k].y - m) + __expf(v[k].z - m) + __expf(v[k].w - m);
  if (has6)
    s += __expf(v[6].x - m) + __expf(v[6].y - m) + __expf(v[6].z - m) + __expf(v[6].w - m);
  if (hashead) s += __expf(head_v - m);
  if (hastail) s += __expf(tail_v - m);

#pragma unroll
  for (int o = 32; o; o >>= 1) s += __shfl_xor(s, o);
  if ((tid & 63) == 0) reds[tid >> 6] = s;
  __syncthreads();

  if (tid == 0) {
    s = reds[0] + reds[1] + reds[2] + reds[3];
    const int b = r >> 10, si = r & 1023;
    const int t = x[(b * 1025 + si + 1) * 12 + c];   // target[..., c], in [0,VOCAB)
    const float vt = rowp[t];
    nll[c * NROWS + r] = -(vt - m - __logf(s));
  }
}

// Single block: masked sums of the 7 NLL vectors + constant-f0 MSE + outputs.
// UNCHANGED from the absmax=0.0 round — keep the bit-exact MSE path.
__global__ __launch_bounds__(256) void finalize_kernel(const int* __restrict__ x,
                                                       const float* __restrict__ nll,
                                                       float* __restrict__ out) {
  const int tid = threadIdx.x;

  // f[...,0] is constant: softmax over size-1 axis == 1, so s == 6.0 and
  // f0 = sum_k d[k,0] = 576 * sum_i sin(-i*pi/6)  (tiny fp32 residue).
  float sum_sin = 0.f;
#pragma unroll
  for (int i = 0; i < 12; i++)
    sum_sin += sinf((float)i * -0.52359877559829887f);
  const float cf = sum_sin * 576.0f;

  float acc[9];  // 0: tv, 1..7: losses, 8: mse
#pragma unroll
  for (int q = 0; q < 9; q++) acc[q] = 0.f;

  for (int r = tid; r < NROWS; r += 256) {
    const int b = r >> 10, si = r & 1023;
    const int* tr = x + (b * 1025 + si + 1) * 12;
    const float mask = (tr[0] != 0) ? 1.f : 0.f;
    acc[0] += mask;
#pragma unroll
    for (int hh = 0; hh < 7; hh++)
      acc[1 + hh] += nll[hh * NROWS + r] * mask;
    const float d = cf - (float)tr[11];
    acc[8] += d * d * mask;
  }

  __shared__ float red[9][4];
#pragma unroll
  for (int q = 0; q < 9; q++) {
    float v = acc[q];
#pragma unroll
    for (int o = 32; o; o >>= 1) v += __shfl_xor(v, o);
    if ((tid & 63) == 0) red[q][tid >> 6] = v;
  }
  __syncthreads();

  if (tid == 0) {
    float tot[9];
#pragma unroll
    for (int q = 0; q < 9; q++)
      tot[q] = red[q][0] + red[q][1] + red[q][2] + red[q][3];
    const float tv  = tot[0];
    const float inv = (tv == 0.f) ? 0.f : 1.f / tv;   // where(tv==0, 0, ·/tv)
#pragma unroll
    for (int hh = 0; hh < 7; hh++) out[hh] = tot[1 + hh] * inv;
    out[7] = tot[8] * inv;
  }
}

extern "C" void kernel_launch(void* const* d_in, const int* in_sizes, int n_in,
                              void* d_out, int out_size, void* d_ws, size_t ws_size,
                              hipStream_t stream) {
  const int* x = (const int*)d_in[0];
  Heads h;
  for (int i = 0; i < 7; i++) h.p[i] = (const float*)d_in[1 + i];

  float* nll = (float*)d_ws;          // 7*2048 floats = 56 KB
  float* out = (float*)d_out;         // 8 floats

  row_nll_kernel<<<7 * NROWS, 256, 0, stream>>>(h, x, nll);
  finalize_kernel<<<1, 256, 0, stream>>>(x, nll, out);
}